// Round 1
// baseline (1178.645 us; speedup 1.0000x reference)
//
#include <hip/hip_runtime.h>
#include <hip/hip_bf16.h>
#include <cstdint>

#define B_ 128
#define U_ 2048
#define L_ 512
#define KG 6144      // GEMM K  (2 * 3072)
#define JD 8192      // GEMM N  (4 * 2048)

// workspace layout (bytes)
#define A_BYTES   (B_ * KG * 2)        // 1,572,864  bf16 xh
#define IFGO_OFF  A_BYTES
#define IFGO_BYTES (B_ * JD * 4)       // 4,194,304  f32 ifgo
#define LOG_OFF   (IFGO_OFF + IFGO_BYTES)

// d_out layout (float offsets): x_out, h_out, c_out, new_ctx
#define HOUT_OFF  (B_ * 2 * U_)        // 524288
#define COUT_OFF  (HOUT_OFF + B_ * U_) // 786432
#define CTX_OFF   (COUT_OFF + B_ * U_) // 1048576

typedef __bf16 bf16_t;
typedef bf16_t bf16x8 __attribute__((ext_vector_type(8)));
typedef float  f32x4  __attribute__((ext_vector_type(4)));

__device__ __forceinline__ unsigned short f2bf(float f) {
  uint32_t x = __builtin_bit_cast(uint32_t, f);
  x += 0x7fffu + ((x >> 16) & 1u);   // RNE
  return (unsigned short)(x >> 16);
}

// ---------------------------------------------------------------- k_prep
// Build A = xh in bf16: A[b][k*3072 + sec*1024 + uu], sec: 0=h,1=x,2=context
__global__ void k_prep(const float* __restrict__ x, const float* __restrict__ h,
                       const float* __restrict__ ctx, unsigned short* __restrict__ A) {
  int t = blockIdx.x * blockDim.x + threadIdx.x;   // 196608 threads, 4 elems each
  int idx = t * 4;
  int b = idx / KG;
  int d = idx - b * KG;
  int k = (d >= 3072) ? 1 : 0;
  int off = d - k * 3072;
  int sec = off >> 10;
  int u = k * 1024 + (off & 1023);
  const float* src = (sec == 0) ? h : ((sec == 1) ? x : ctx);
  float4 v = *(const float4*)(src + (size_t)b * U_ + u);
  ushort4 o;
  o.x = f2bf(v.x); o.y = f2bf(v.y); o.z = f2bf(v.z); o.w = f2bf(v.w);
  *(ushort4*)(A + idx) = o;
}

// ---------------------------------------------------------------- k_gemm
// C[128][8192] = A[128][6144](bf16) @ B[6144][8192], B col j=n*2048+f comes
// from W[(k*4+n)][d][f]. Block: BN=32 cols, BM=128 (all rows), BK=32.
// 512 threads = 8 waves; wave w computes rows [w*16, w*16+16) x 32 cols
// via two 16x16x32 bf16 MFMAs per K-step.
#define LDA 40   // bf16 units; 80B row stride -> 16B-aligned b128, bank-spread
#define LDB 40
__global__ __launch_bounds__(512, 1) void k_gemm(const unsigned short* __restrict__ A,
                                                 const float* __restrict__ W,
                                                 float* __restrict__ ifgo) {
  __shared__ unsigned short As[128 * LDA];
  __shared__ unsigned short Bs[32 * LDB];
  const int t = threadIdx.x;
  const int ncol = blockIdx.x * 32;
  const int nout = ncol >> 11;            // which n-chunk (0..3)
  const int fbase = ncol & 2047;
  const float* W0 = W + (size_t)nout * 3072 * 2048 + fbase;        // k=0 block
  const float* W1 = W + (size_t)(4 + nout) * 3072 * 2048 + fbase;  // k=1 block

  // staging roles
  const int arow = t >> 2, achunk = t & 3;        // A: 128 rows x 4 chunks of 8 bf16
  const int wrow = t >> 4, wf = (t & 15) * 2;     // W: 32 rows x 16 float2
  const unsigned short* Ag = A + (size_t)arow * KG + achunk * 8;

  // compute roles
  const int lane = t & 63;
  const int wv = t >> 6;                          // 0..7
  const int row16 = lane & 15, quad = lane >> 4;
  const int m = wv * 16 + row16;
  const unsigned short* aptr  = &As[m * LDA + quad * 8];
  const unsigned short* bptr0 = &Bs[row16 * LDB + quad * 8];
  const unsigned short* bptr1 = &Bs[(16 + row16) * LDB + quad * 8];

  f32x4 acc0 = {0.f, 0.f, 0.f, 0.f};
  f32x4 acc1 = {0.f, 0.f, 0.f, 0.f};

  // prologue: prefetch K-step 0
  uint4 aReg = *(const uint4*)(Ag);
  float2 wReg = *(const float2*)(W0 + (size_t)wrow * 2048 + wf);

  for (int it = 0; it < 192; ++it) {
    // drain prefetched regs into LDS
    *(uint4*)&As[arow * LDA + achunk * 8] = aReg;
    Bs[wf * LDB + wrow]       = f2bf(wReg.x);   // transpose: Bs[n][k]
    Bs[(wf + 1) * LDB + wrow] = f2bf(wReg.y);
    __syncthreads();
    // prefetch next K-step (lands after MFMAs issue)
    if (it + 1 < 192) {
      int kk = (it + 1) * 32;
      aReg = *(const uint4*)(Ag + kk);
      int krow = kk + wrow;
      const float* s = (krow < 3072) ? (W0 + (size_t)krow * 2048)
                                     : (W1 + (size_t)(krow - 3072) * 2048);
      wReg = *(const float2*)(s + wf);
    }
    bf16x8 av  = *(const bf16x8*)aptr;
    bf16x8 bv0 = *(const bf16x8*)bptr0;
    bf16x8 bv1 = *(const bf16x8*)bptr1;
    acc0 = __builtin_amdgcn_mfma_f32_16x16x32_bf16(av, bv0, acc0, 0, 0, 0);
    acc1 = __builtin_amdgcn_mfma_f32_16x16x32_bf16(av, bv1, acc1, 0, 0, 0);
    __syncthreads();
  }

  // epilogue: C/D layout col=lane&15, row=quad*4+reg
  int brow = wv * 16 + quad * 4;
  #pragma unroll
  for (int r = 0; r < 4; ++r) {
    ifgo[(size_t)(brow + r) * JD + ncol + row16]      = acc0[r];
    ifgo[(size_t)(brow + r) * JD + ncol + 16 + row16] = acc1[r];
  }
}

// ---------------------------------------------------------------- k_gates
__global__ void k_gates(const float* __restrict__ ifgo, const float* __restrict__ c,
                        const float* __restrict__ ctx, float* __restrict__ out) {
  int idx = blockIdx.x * blockDim.x + threadIdx.x;   // 262144 = 128*2048
  int b = idx >> 11;
  int u = idx & 2047;
  int n = u >> 9;
  int uu = u & 511;
  size_t base = (size_t)b * JD + n * 2048 + uu;
  float iv = ifgo[base];
  float fv = ifgo[base + 512];
  float gv = ifgo[base + 1024];
  float ov = ifgo[base + 1536];
  float si = 1.f / (1.f + __expf(-iv));
  float sf = 1.f / (1.f + __expf(-fv));
  float so = 1.f / (1.f + __expf(-ov));
  float tg = tanhf(gv);
  float nc = sf * c[idx] + si * tg;
  float nh = so * tanhf(nc);
  out[HOUT_OFF + idx] = nh;
  out[COUT_OFF + idx] = nc;
  out[(size_t)b * 4096 + u] = nh;                 // x_out first half
  out[(size_t)b * 4096 + 2048 + u] = ctx[idx];    // x_out second half
}

// ---------------------------------------------------------------- k_logits
// one wave per (b,l): dot(enc_attn[b,l,:], h_out[b,:]) over U=2048
__global__ __launch_bounds__(256) void k_logits(const float* __restrict__ ea,
                                                const float* __restrict__ hout,
                                                float* __restrict__ logits) {
  int wv = threadIdx.x >> 6, lane = threadIdx.x & 63;
  int p = blockIdx.x * 4 + wv;            // (b,l) pair index
  int b = p >> 9, l = p & 511;
  const float* e  = ea + ((size_t)b * L_ + l) * U_;
  const float* hb = hout + (size_t)b * U_;
  float acc = 0.f;
  #pragma unroll
  for (int i = 0; i < 8; ++i) {
    float4 ev = *(const float4*)(e + i * 256 + lane * 4);
    float4 hv = *(const float4*)(hb + i * 256 + lane * 4);
    acc += ev.x * hv.x + ev.y * hv.y + ev.z * hv.z + ev.w * hv.w;
  }
  #pragma unroll
  for (int off = 32; off > 0; off >>= 1) acc += __shfl_down(acc, off);
  if (lane == 0) logits[p] = acc;
}

// ---------------------------------------------------------------- k_ctx
// per (b, 512-wide u-chunk): softmax over L in-block, then score @ enc_out
__global__ __launch_bounds__(256) void k_ctx(const float* __restrict__ logits,
                                             const float* __restrict__ eo,
                                             float* __restrict__ out) {
  __shared__ float wls[512];
  __shared__ float red[8];
  int t = threadIdx.x;
  int b = blockIdx.x >> 2;
  int u0 = (blockIdx.x & 3) * 512;
  float x0 = logits[b * 512 + t];
  float x1 = logits[b * 512 + 256 + t];
  // block max
  float mx = fmaxf(x0, x1);
  #pragma unroll
  for (int off = 32; off > 0; off >>= 1) mx = fmaxf(mx, __shfl_down(mx, off));
  if ((t & 63) == 0) red[t >> 6] = mx;
  __syncthreads();
  mx = fmaxf(fmaxf(red[0], red[1]), fmaxf(red[2], red[3]));
  float e0 = __expf(x0 - mx), e1 = __expf(x1 - mx);
  wls[t] = e0; wls[256 + t] = e1;
  float s = e0 + e1;
  #pragma unroll
  for (int off = 32; off > 0; off >>= 1) s += __shfl_down(s, off);
  __syncthreads();
  if ((t & 63) == 0) red[4 + (t >> 6)] = s;
  __syncthreads();
  float inv = 1.f / (red[4] + red[5] + red[6] + red[7]);

  const float* ep = eo + (size_t)b * L_ * U_ + u0 + t * 2;
  float2 acc = {0.f, 0.f};
  #pragma unroll 4
  for (int l = 0; l < 512; ++l) {
    float w = wls[l];
    float2 v = *(const float2*)(ep + (size_t)l * U_);
    acc.x += w * v.x;
    acc.y += w * v.y;
  }
  float2 o; o.x = acc.x * inv; o.y = acc.y * inv;
  *(float2*)(out + CTX_OFF + (size_t)b * U_ + u0 + t * 2) = o;
}

// ---------------------------------------------------------------- launch
extern "C" void kernel_launch(void* const* d_in, const int* in_sizes, int n_in,
                              void* d_out, int out_size, void* d_ws, size_t ws_size,
                              hipStream_t stream) {
  const float* x   = (const float*)d_in[0];
  const float* h   = (const float*)d_in[1];
  const float* c   = (const float*)d_in[2];
  const float* ctx = (const float*)d_in[3];
  const float* W   = (const float*)d_in[4];
  const float* ea  = (const float*)d_in[5];
  const float* eo  = (const float*)d_in[6];
  float* out = (float*)d_out;
  unsigned short* Abf = (unsigned short*)d_ws;
  float* ifgo   = (float*)((char*)d_ws + IFGO_OFF);
  float* logits = (float*)((char*)d_ws + LOG_OFF);

  hipLaunchKernelGGL(k_prep,   dim3(768),   dim3(256), 0, stream, x, h, ctx, Abf);
  hipLaunchKernelGGL(k_gemm,   dim3(256),   dim3(512), 0, stream, Abf, W, ifgo);
  hipLaunchKernelGGL(k_gates,  dim3(1024),  dim3(256), 0, stream, ifgo, c, ctx, out);
  hipLaunchKernelGGL(k_logits, dim3(16384), dim3(256), 0, stream, ea, out + HOUT_OFF, logits);
  hipLaunchKernelGGL(k_ctx,    dim3(512),   dim3(256), 0, stream, logits, eo, out);
}